// Round 5
// baseline (2976.077 us; speedup 1.0000x reference)
//
#include <hip/hip_runtime.h>
#include <math.h>

#define N_EDGESC  1048576
#define N_GRAPHSC 8192
#define NPG 32     // nodes per graph
#define EPG 128    // edges per graph
#define FXD 78
#define F2C 156
#define F3C 312
#define GHC 156    // Wg1 out
#define GOC 128    // Wg2 out
#define HS  36     // padded node-stride
#define RBC 8      // rows per block in fused cell body
#define RBK 16     // rows per block in head kernel

// ---------------------------------------------------------------------------
// IN-PLACE multi-row A-aggregation: H[k][r] <- sum_c H[k][c] * A[r][c].
template<int FIN, int ROWS>
__device__ __forceinline__ void a_mult_ip(float* __restrict__ H,
                                          const float* __restrict__ As, int t) {
  const int r0 = (t & 7) * 4;
  const int g = t >> 3;
  float acc[ROWS][4];
  float* rowp[ROWS];
  bool valid[ROWS];
#pragma unroll
  for (int j = 0; j < ROWS; ++j) {
    int k = g + 32 * j;
    valid[j] = (k < FIN);
    rowp[j] = H + k * HS;
    acc[j][0] = acc[j][1] = acc[j][2] = acc[j][3] = 0.f;
  }
#pragma unroll
  for (int c = 0; c < NPG; c += 4) {
    float4 a0 = *(const float4*)(As + (c + 0) * HS + r0);
    float4 a1 = *(const float4*)(As + (c + 1) * HS + r0);
    float4 a2 = *(const float4*)(As + (c + 2) * HS + r0);
    float4 a3 = *(const float4*)(As + (c + 3) * HS + r0);
#pragma unroll
    for (int j = 0; j < ROWS; ++j) {
      if (valid[j]) {
        float4 h4 = *(const float4*)(rowp[j] + c);
        acc[j][0] = fmaf(h4.x, a0.x, acc[j][0]); acc[j][1] = fmaf(h4.x, a0.y, acc[j][1]);
        acc[j][2] = fmaf(h4.x, a0.z, acc[j][2]); acc[j][3] = fmaf(h4.x, a0.w, acc[j][3]);
        acc[j][0] = fmaf(h4.y, a1.x, acc[j][0]); acc[j][1] = fmaf(h4.y, a1.y, acc[j][1]);
        acc[j][2] = fmaf(h4.y, a1.z, acc[j][2]); acc[j][3] = fmaf(h4.y, a1.w, acc[j][3]);
        acc[j][0] = fmaf(h4.z, a2.x, acc[j][0]); acc[j][1] = fmaf(h4.z, a2.y, acc[j][1]);
        acc[j][2] = fmaf(h4.z, a2.z, acc[j][2]); acc[j][3] = fmaf(h4.z, a2.w, acc[j][3]);
        acc[j][0] = fmaf(h4.w, a3.x, acc[j][0]); acc[j][1] = fmaf(h4.w, a3.y, acc[j][1]);
        acc[j][2] = fmaf(h4.w, a3.z, acc[j][2]); acc[j][3] = fmaf(h4.w, a3.w, acc[j][3]);
      }
    }
  }
#pragma unroll
  for (int j = 0; j < ROWS; ++j) {
    if (valid[j]) {
      float4 o = {acc[j][0], acc[j][1], acc[j][2], acc[j][3]};
      *(float4*)(rowp[j] + r0) = o;
    }
  }
}

// ---------------------------------------------------------------------------
template<int VEC>
__device__ __forceinline__ void loadWv(const float* __restrict__ wp, float* wv) {
  if constexpr (VEC == 8) {
    float4 a = *(const float4*)wp; float4 b = *(const float4*)(wp + 4);
    wv[0] = a.x; wv[1] = a.y; wv[2] = a.z; wv[3] = a.w;
    wv[4] = b.x; wv[5] = b.y; wv[6] = b.z; wv[7] = b.w;
  } else if constexpr (VEC == 6) {
    float2 a = *(const float2*)wp; float2 b = *(const float2*)(wp + 2);
    float2 c = *(const float2*)(wp + 4);
    wv[0] = a.x; wv[1] = a.y; wv[2] = b.x; wv[3] = b.y; wv[4] = c.x; wv[5] = c.y;
  } else if constexpr (VEC == 4) {
    float4 a = *(const float4*)wp;
    wv[0] = a.x; wv[1] = a.y; wv[2] = a.z; wv[3] = a.w;
  } else {
    float2 a = *(const float2*)wp;
    wv[0] = a.x; wv[1] = a.y;
  }
}

// Hout[f][n] = act( sum_k AH[k][n]*W[k][f] + b[f] ). Software-pipelined
// (rotation depth B): batch b+1's LDS/global loads issue before batch b's
// FMAs -> W L2-hit latency (~200cyc) overlapped by the FMA body.
template<int FIN, int FOUT, int VEC, int B, bool RELU, bool POOL>
__device__ __forceinline__ void mm_layer(const float* __restrict__ AH,
                                         const float* __restrict__ W,
                                         const float* __restrict__ bias,
                                         float* __restrict__ Hout,
                                         unsigned* __restrict__ gmax, int t) {
  const int n0 = (t & 7) * 4;
  constexpr int NF = FOUT / VEC;
  constexpr int NB = FIN / B;
  constexpr int REM = FIN % B;
  for (int fb = t >> 3; fb < NF; fb += 32) {
    const int f0 = fb * VEC;
    float acc[VEC][4];
#pragma unroll
    for (int v = 0; v < VEC; ++v) {
#pragma unroll
      for (int i = 0; i < 4; ++i) acc[v][i] = 0.f;
    }
    float4 hb[B];
    float wb[B][VEC];
#pragma unroll
    for (int u = 0; u < B; ++u) {
      hb[u] = *(const float4*)(AH + u * HS + n0);
      loadWv<VEC>(W + (size_t)u * FOUT + f0, wb[u]);
    }
#pragma unroll 2
    for (int b = 0; b < NB; ++b) {
      float4 hn[B];
      float wn[B][VEC];
      const bool more = (b + 1 < NB);
      if (more) {
        const int k0 = (b + 1) * B;
#pragma unroll
        for (int u = 0; u < B; ++u) {
          hn[u] = *(const float4*)(AH + (k0 + u) * HS + n0);
          loadWv<VEC>(W + (size_t)(k0 + u) * FOUT + f0, wn[u]);
        }
      }
#pragma unroll
      for (int u = 0; u < B; ++u) {
#pragma unroll
        for (int v = 0; v < VEC; ++v) {
          float w = wb[u][v];
          acc[v][0] = fmaf(hb[u].x, w, acc[v][0]);
          acc[v][1] = fmaf(hb[u].y, w, acc[v][1]);
          acc[v][2] = fmaf(hb[u].z, w, acc[v][2]);
          acc[v][3] = fmaf(hb[u].w, w, acc[v][3]);
        }
      }
      if (more) {
#pragma unroll
        for (int u = 0; u < B; ++u) {
          hb[u] = hn[u];
#pragma unroll
          for (int v = 0; v < VEC; ++v) wb[u][v] = wn[u][v];
        }
      }
    }
#pragma unroll
    for (int r = 0; r < REM; ++r) {
      const int k = NB * B + r;
      float4 h = *(const float4*)(AH + k * HS + n0);
      float wv[VEC];
      loadWv<VEC>(W + (size_t)k * FOUT + f0, wv);
#pragma unroll
      for (int v = 0; v < VEC; ++v) {
        float w = wv[v];
        acc[v][0] = fmaf(h.x, w, acc[v][0]);
        acc[v][1] = fmaf(h.y, w, acc[v][1]);
        acc[v][2] = fmaf(h.z, w, acc[v][2]);
        acc[v][3] = fmaf(h.w, w, acc[v][3]);
      }
    }
#pragma unroll
    for (int v = 0; v < VEC; ++v) {
      float bb = bias[f0 + v];
      float o0 = acc[v][0] + bb, o1 = acc[v][1] + bb;
      float o2 = acc[v][2] + bb, o3 = acc[v][3] + bb;
      if (RELU) {
        o0 = fmaxf(o0, 0.f); o1 = fmaxf(o1, 0.f);
        o2 = fmaxf(o2, 0.f); o3 = fmaxf(o3, 0.f);
      }
      if constexpr (POOL) {
        float m = fmaxf(fmaxf(o0, o1), fmaxf(o2, o3));
        atomicMax(&gmax[f0 + v], __float_as_uint(m));  // relu'd >= 0 -> monotone
      } else {
        float4 o = {o0, o1, o2, o3};
        *(float4*)(Hout + (f0 + v) * HS + n0) = o;
      }
    }
  }
}

// ---------------------------------------------------------------------------
// Cell MLP body (fused into drug grid as blockIdx.y==2). RBC=8 rows/block.
// LDS overlay: U = SMEM[0..4095], h2 = SMEM[4096..6143] (fits drug's 9576).
__device__ __forceinline__ void cell_body(float* __restrict__ SMEM,
                                          const float* __restrict__ cell,
                                          const float* __restrict__ Wr1, const float* __restrict__ br1,
                                          const float* __restrict__ Wr2, const float* __restrict__ br2,
                                          const float* __restrict__ Wr3, const float* __restrict__ br3,
                                          float* __restrict__ cout) {
  float* U = SMEM;            // 512*RBC = 4096 floats
  float* h2 = SMEM + 4096;    // 256*RBC = 2048 floats
  const int t = threadIdx.x;
  const int R = blockIdx.x * RBC;
  const int r0 = (t & 1) * 4;
  const int f = t >> 1;  // [0,128)

  float acc[4][4];
#pragma unroll
  for (int i = 0; i < 4; ++i)
#pragma unroll
    for (int j = 0; j < 4; ++j) acc[i][j] = 0.f;

  for (int k0 = 0; k0 < 1000; k0 += 200) {
    __syncthreads();
    for (int i = t; i < 400; i += 256) {       // 8 rows x 50 float4
      int r = i / 50, k4 = i - r * 50;
      float4 v = *(const float4*)(cell + (size_t)(R + r) * 1000 + k0 + k4 * 4);
      int kk = k4 * 4;
      U[(kk + 0) * RBC + r] = v.x; U[(kk + 1) * RBC + r] = v.y;
      U[(kk + 2) * RBC + r] = v.z; U[(kk + 3) * RBC + r] = v.w;
    }
    __syncthreads();
#pragma unroll 4
    for (int k = 0; k < 200; ++k) {
      float4 h = *(const float4*)(U + k * RBC + r0);
      const float* wr = Wr1 + (size_t)(k0 + k) * 512 + f;
#pragma unroll
      for (int j = 0; j < 4; ++j) {
        float w = wr[j * 128];
        acc[0][j] = fmaf(h.x, w, acc[0][j]);
        acc[1][j] = fmaf(h.y, w, acc[1][j]);
        acc[2][j] = fmaf(h.z, w, acc[2][j]);
        acc[3][j] = fmaf(h.w, w, acc[3][j]);
      }
    }
  }
  __syncthreads();   // ct region dead -> U becomes h1
#pragma unroll
  for (int j = 0; j < 4; ++j) {
    int ff = f + j * 128;
    float bb = br1[ff];
    float4 o;
    o.x = fmaxf(acc[0][j] + bb, 0.f); o.y = fmaxf(acc[1][j] + bb, 0.f);
    o.z = fmaxf(acc[2][j] + bb, 0.f); o.w = fmaxf(acc[3][j] + bb, 0.f);
    *(float4*)(U + ff * RBC + r0) = o;
  }
  __syncthreads();

  float a2[4][2];
#pragma unroll
  for (int i = 0; i < 4; ++i) { a2[i][0] = 0.f; a2[i][1] = 0.f; }
#pragma unroll 4
  for (int k = 0; k < 512; ++k) {
    float4 h = *(const float4*)(U + k * RBC + r0);
    const float* wr = Wr2 + (size_t)k * 256 + f;
#pragma unroll
    for (int j = 0; j < 2; ++j) {
      float w = wr[j * 128];
      a2[0][j] = fmaf(h.x, w, a2[0][j]);
      a2[1][j] = fmaf(h.y, w, a2[1][j]);
      a2[2][j] = fmaf(h.z, w, a2[2][j]);
      a2[3][j] = fmaf(h.w, w, a2[3][j]);
    }
  }
#pragma unroll
  for (int j = 0; j < 2; ++j) {  // h2 disjoint from U: no barrier needed
    int ff = f + j * 128;
    float bb = br2[ff];
    float4 o;
    o.x = fmaxf(a2[0][j] + bb, 0.f); o.y = fmaxf(a2[1][j] + bb, 0.f);
    o.z = fmaxf(a2[2][j] + bb, 0.f); o.w = fmaxf(a2[3][j] + bb, 0.f);
    *(float4*)(h2 + ff * RBC + r0) = o;
  }
  __syncthreads();

  float a3[4] = {0.f, 0.f, 0.f, 0.f};
#pragma unroll 4
  for (int k = 0; k < 256; ++k) {
    float4 h = *(const float4*)(h2 + k * RBC + r0);
    float w = Wr3[(size_t)k * 128 + f];
    a3[0] = fmaf(h.x, w, a3[0]); a3[1] = fmaf(h.y, w, a3[1]);
    a3[2] = fmaf(h.z, w, a3[2]); a3[3] = fmaf(h.w, w, a3[3]);
  }
  float bb = br3[f];
#pragma unroll
  for (int i = 0; i < 4; ++i)
    cout[(size_t)(R + r0 + i) * GOC + f] = a3[i] + bb;  // no relu
}

// ---------------------------------------------------------------------------
// Fused kernel: blockIdx.y 0/1 = drug branches (one block per graph),
// blockIdx.y==2 & x<1024 = cell MLP (fills the dispatch tail).
// Union LDS 38304 B -> 4 blocks/CU.
__global__ __launch_bounds__(256, 4)
void drug_kernel(const float* __restrict__ x1, const int* __restrict__ ei1,
                 const float* __restrict__ x2, const int* __restrict__ ei2,
                 const float* __restrict__ W1, const float* __restrict__ b1,
                 const float* __restrict__ W2, const float* __restrict__ b2,
                 const float* __restrict__ W3, const float* __restrict__ b3,
                 const float* __restrict__ Wg1, const float* __restrict__ bg1,
                 const float* __restrict__ Wg2, const float* __restrict__ bg2,
                 const float* __restrict__ cel,
                 const float* __restrict__ Wr1, const float* __restrict__ br1,
                 const float* __restrict__ Wr2, const float* __restrict__ br2,
                 const float* __restrict__ Wr3, const float* __restrict__ br3,
                 float* __restrict__ gout, float* __restrict__ cout) {
  __shared__ __align__(16) float SMEM[9576];   // 38304 B union
  const int t = threadIdx.x;
  const int drug = blockIdx.y;

  if (drug == 2) {
    if (blockIdx.x < N_GRAPHSC / RBC)
      cell_body(SMEM, cel, Wr1, br1, Wr2, br2, Wr3, br3, cout);
    return;
  }

  float* X  = SMEM;          // 156*36 = 5616 floats
  float* Y  = SMEM + 5616;   //  78*36 = 2808 floats
  float* As = SMEM + 8424;   //  32*36 = 1152 floats
  // aliases into Y (lifetimes disjoint):
  float* deg = Y;
  float* gbuf = Y;
  unsigned* gbufU = (unsigned*)Y;
  float* gg = Y + 512;

  const int gid = blockIdx.x;
  const float* __restrict__ x = drug ? x2 : x1;
  const int* __restrict__ ei = drug ? ei2 : ei1;
  const int nbase = gid * NPG;

  // ---- P0: zero deg + As, load x^T -> X
  if (t < NPG) deg[t] = 0.f;
  for (int i = t; i < NPG * HS; i += 256) As[i] = 0.f;
  const float* xg = x + (size_t)gid * (NPG * FXD);
  for (int i = t; i < (NPG * FXD) / 4; i += 256) {
    float4 v = ((const float4*)xg)[i];
    const float* vp = (const float*)&v;
    int idx = i * 4;
#pragma unroll
    for (int j = 0; j < 4; ++j) {
      int id2 = idx + j;
      int n = id2 / FXD;
      int k = id2 - n * FXD;
      X[k * HS + n] = vp[j];
    }
  }
  int s = 0, d = 0;
  if (t < EPG) {
    s = ei[(size_t)gid * EPG + t] - nbase;
    d = ei[(size_t)N_EDGESC + (size_t)gid * EPG + t] - nbase;
  }
  __syncthreads();
  if (t < EPG) atomicAdd(&deg[s], 1.0f);
  __syncthreads();
  if (t < EPG) {
    float w = rsqrtf(deg[s] + 1.0f) * rsqrtf(deg[d] + 1.0f);
    atomicAdd(&As[d * HS + s], w);   // A[s][d]: msg d->s
  }
  if (t < NPG) atomicAdd(&As[t * HS + t], 1.0f / (deg[t] + 1.0f));
  __syncthreads();

  // ---- layer 1
  a_mult_ip<FXD, 3>(X, As, t);
  __syncthreads();
  mm_layer<FXD, FXD, 6, 2, true, false>(X, W1, b1, Y, nullptr, t);  // deg dead
  __syncthreads();
  // ---- layer 2
  a_mult_ip<FXD, 3>(Y, As, t);
  __syncthreads();
  mm_layer<FXD, F2C, 4, 4, true, false>(Y, W2, b2, X, nullptr, t);
  __syncthreads();
  // ---- layer 3 + pool (Y dead: gbuf lives there)
  a_mult_ip<F2C, 5>(X, As, t);
  for (int i = t; i < F3C; i += 256) gbufU[i] = 0u;
  __syncthreads();
  mm_layer<F2C, F3C, 8, 2, true, true>(X, W3, b3, nullptr, gbufU, t);
  __syncthreads();

  // ---- graph MLP
  if (t < GHC) {
    float acc = 0.f;
#pragma unroll 2
    for (int k = 0; k < F3C; k += 4) {
      float4 gv = *(const float4*)(gbuf + k);
      acc = fmaf(gv.x, Wg1[(k + 0) * GHC + t], acc);
      acc = fmaf(gv.y, Wg1[(k + 1) * GHC + t], acc);
      acc = fmaf(gv.z, Wg1[(k + 2) * GHC + t], acc);
      acc = fmaf(gv.w, Wg1[(k + 3) * GHC + t], acc);
    }
    gg[t] = fmaxf(acc + bg1[t], 0.f);
  }
  __syncthreads();
  if (t < GOC) {
    float acc = 0.f;
#pragma unroll 2
    for (int k = 0; k < GHC; k += 4) {
      float4 gv = *(const float4*)(gg + k);
      acc = fmaf(gv.x, Wg2[(k + 0) * GOC + t], acc);
      acc = fmaf(gv.y, Wg2[(k + 1) * GOC + t], acc);
      acc = fmaf(gv.z, Wg2[(k + 2) * GOC + t], acc);
      acc = fmaf(gv.w, Wg2[(k + 3) * GOC + t], acc);
    }
    gout[((size_t)drug * N_GRAPHSC + gid) * GOC + t] = acc + bg2[t];
  }
}

// ---------------------------------------------------------------------------
// Head: 16 rows/block. U holds xct then h1; h2 separate. ~41.2 KB.
__global__ __launch_bounds__(256, 3)
void head_kernel(const float* __restrict__ g1, const float* __restrict__ g2,
                 const float* __restrict__ cc,
                 const float* __restrict__ Wf1, const float* __restrict__ bf1,
                 const float* __restrict__ Wf2, const float* __restrict__ bf2,
                 const float* __restrict__ Wo, const float* __restrict__ bo,
                 const float* __restrict__ pa, float* __restrict__ out) {
  __shared__ __align__(16) float U[512 * RBK];   // 32768 B
  __shared__ __align__(16) float h2[128 * RBK];  //  8192 B
  __shared__ float ssq[RBK];
  __shared__ float scal[RBK];
  __shared__ float red[256];

  const int t = threadIdx.x;
  const int R = blockIdx.x * RBK;
  if (t < RBK) ssq[t] = 0.f;
  __syncthreads();
  for (int i = t; i < 1536; i += 256) {   // 16 rows x 96 float4
    int r = i / 96, q = i - r * 96;
    int col = q * 4;
    const float* src;
    int c2;
    if (col < 128)      { src = g1; c2 = col; }
    else if (col < 256) { src = g2; c2 = col - 128; }
    else                { src = cc; c2 = col - 256; }
    float4 v = *(const float4*)(src + (size_t)(R + r) * GOC + c2);
    U[(col + 0) * RBK + r] = v.x; U[(col + 1) * RBK + r] = v.y;
    U[(col + 2) * RBK + r] = v.z; U[(col + 3) * RBK + r] = v.w;
    atomicAdd(&ssq[r], v.x * v.x + v.y * v.y + v.z * v.z + v.w * v.w);
  }
  __syncthreads();
  if (t < RBK) scal[t] = 1.0f / fmaxf(sqrtf(ssq[t]), 1e-12f);
  __syncthreads();

  const float a = pa[0];
  const int r0 = (t & 3) * 4;
  const int f = t >> 2;  // [0,64)

  float acc[4][8];
#pragma unroll
  for (int i = 0; i < 4; ++i)
#pragma unroll
    for (int j = 0; j < 8; ++j) acc[i][j] = 0.f;
#pragma unroll 4
  for (int k = 0; k < 384; ++k) {
    float4 h = *(const float4*)(U + k * RBK + r0);
    const float* wr = Wf1 + (size_t)k * 512 + f;
#pragma unroll
    for (int j = 0; j < 8; ++j) {
      float w = wr[j * 64];
      acc[0][j] = fmaf(h.x, w, acc[0][j]);
      acc[1][j] = fmaf(h.y, w, acc[1][j]);
      acc[2][j] = fmaf(h.z, w, acc[2][j]);
      acc[3][j] = fmaf(h.w, w, acc[3][j]);
    }
  }
  __syncthreads();   // xct dead -> U becomes h1
#pragma unroll
  for (int j = 0; j < 8; ++j) {
    int ff = f + j * 64;
    float bb = bf1[ff];
    float4 o;
    float v0 = acc[0][j] * scal[r0 + 0] + bb; o.x = v0 >= 0.f ? v0 : a * v0;
    float v1 = acc[1][j] * scal[r0 + 1] + bb; o.y = v1 >= 0.f ? v1 : a * v1;
    float v2 = acc[2][j] * scal[r0 + 2] + bb; o.z = v2 >= 0.f ? v2 : a * v2;
    float v3 = acc[3][j] * scal[r0 + 3] + bb; o.w = v3 >= 0.f ? v3 : a * v3;
    *(float4*)(U + ff * RBK + r0) = o;
  }
  __syncthreads();

  float a2[4][2];
#pragma unroll
  for (int i = 0; i < 4; ++i) { a2[i][0] = 0.f; a2[i][1] = 0.f; }
#pragma unroll 4
  for (int k = 0; k < 512; ++k) {
    float4 h = *(const float4*)(U + k * RBK + r0);
    const float* wr = Wf2 + (size_t)k * 128 + f;
#pragma unroll
    for (int j = 0; j < 2; ++j) {
      float w = wr[j * 64];
      a2[0][j] = fmaf(h.x, w, a2[0][j]);
      a2[1][j] = fmaf(h.y, w, a2[1][j]);
      a2[2][j] = fmaf(h.z, w, a2[2][j]);
      a2[3][j] = fmaf(h.w, w, a2[3][j]);
    }
  }
  {
#pragma unroll
    for (int j = 0; j < 2; ++j) {   // h2 disjoint from U
      int ff = f + j * 64;
      float bb = bf2[ff];
#pragma unroll
      for (int i = 0; i < 4; ++i) {
        float v = a2[i][j] + bb;
        v = v >= 0.f ? v : a * v;
        h2[ff * RBK + (r0 + i)] = v;
      }
    }
  }
  __syncthreads();

  {
    int rr = t >> 4, kp = t & 15;
    float p = 0.f;
#pragma unroll
    for (int jj = 0; jj < 8; ++jj) {
      int k = kp + 16 * jj;
      p = fmaf(h2[k * RBK + rr], Wo[k], p);
    }
    red[t] = p;
  }
  __syncthreads();
  if (t < RBK) {
    float ssum = bo[0];
#pragma unroll
    for (int i = 0; i < 16; ++i) ssum += red[t * 16 + i];
    out[R + t] = 1.0f / (1.0f + expf(-ssum));
  }
}

// ---------------------------------------------------------------------------
extern "C" void kernel_launch(void* const* d_in, const int* in_sizes, int n_in,
                              void* d_out, int out_size, void* d_ws, size_t ws_size,
                              hipStream_t stream) {
  const float* x1  = (const float*)d_in[0];
  const int*   ei1 = (const int*)d_in[1];
  const float* x2  = (const float*)d_in[2];
  const int*   ei2 = (const int*)d_in[3];
  const float* cel = (const float*)d_in[4];
  const float* W1  = (const float*)d_in[7];
  const float* b1  = (const float*)d_in[8];
  const float* W2  = (const float*)d_in[9];
  const float* b2  = (const float*)d_in[10];
  const float* W3  = (const float*)d_in[11];
  const float* b3  = (const float*)d_in[12];
  const float* Wg1 = (const float*)d_in[13];
  const float* bg1 = (const float*)d_in[14];
  const float* Wg2 = (const float*)d_in[15];
  const float* bg2 = (const float*)d_in[16];
  const float* Wr1 = (const float*)d_in[17];
  const float* br1 = (const float*)d_in[18];
  const float* Wr2 = (const float*)d_in[19];
  const float* br2 = (const float*)d_in[20];
  const float* Wr3 = (const float*)d_in[21];
  const float* br3 = (const float*)d_in[22];
  const float* Wf1 = (const float*)d_in[23];
  const float* bf1 = (const float*)d_in[24];
  const float* Wf2 = (const float*)d_in[25];
  const float* bf2 = (const float*)d_in[26];
  const float* Wo  = (const float*)d_in[27];
  const float* bo  = (const float*)d_in[28];
  const float* pa  = (const float*)d_in[29];

  float* ws    = (float*)d_ws;
  float* g1buf = ws;
  float* g2buf = ws + (size_t)N_GRAPHSC * GOC;
  float* cbuf  = ws + (size_t)2 * N_GRAPHSC * GOC;
  float* outp  = (float*)d_out;

  dim3 dgrid(N_GRAPHSC, 3);
  drug_kernel<<<dgrid, dim3(256), 0, stream>>>(
      x1, ei1, x2, ei2, W1, b1, W2, b2, W3, b3, Wg1, bg1, Wg2, bg2,
      cel, Wr1, br1, Wr2, br2, Wr3, br3, g1buf, cbuf);
  head_kernel<<<dim3(N_GRAPHSC / RBK), dim3(256), 0, stream>>>(
      g1buf, g2buf, cbuf, Wf1, bf1, Wf2, bf2, Wo, bo, pa, outp);
}

// Round 6
// 1715.751 us; speedup vs baseline: 1.7346x; 1.7346x over previous
//
#include <hip/hip_runtime.h>
#include <hip/hip_bf16.h>
#include <math.h>

#define N_EDGESC  1048576
#define N_GRAPHSC 8192
#define NPG 32     // nodes per graph
#define EPG 128    // edges per graph
#define FXD 78
#define F2C 156
#define F3C 312
#define GHC 156    // Wg1 out
#define GOC 128    // Wg2 out
#define HS  36     // padded node-stride (fp32 k-major tiles)
#define HBS 168    // Hb row stride in shorts (84 dwords; m*84%32 cycles 8 banks)
#define RBK 16     // rows per block in MLP kernels

typedef __attribute__((ext_vector_type(8))) short short8v;   // 8 bf16 = 4 VGPR
typedef __attribute__((ext_vector_type(4))) float float4v;

__device__ __forceinline__ short f2bf(float x) {  // RNE truncate f32->bf16 bits
  unsigned u = __float_as_uint(x);
  u += 0x7FFFu + ((u >> 16) & 1u);
  return (short)(u >> 16);
}

// ---------------------------------------------------------------------------
// A-aggregation: reads fp32 k-major H, emits ONLY bf16 node-major Hb[r][k].
// Group g (8 lanes) owns rows k = g+32j; lane covers cols r0..r0+3.
template<int FIN, int ROWS>
__device__ __forceinline__ void a_mult_bf(const float* __restrict__ H,
                                          const float* __restrict__ As,
                                          short* __restrict__ Hb, int t) {
  const int r0 = (t & 7) * 4;
  const int g = t >> 3;
  float acc[ROWS][4];
#pragma unroll
  for (int j = 0; j < ROWS; ++j)
    acc[j][0] = acc[j][1] = acc[j][2] = acc[j][3] = 0.f;
#pragma unroll
  for (int c = 0; c < NPG; c += 4) {
    float4 a0 = *(const float4*)(As + (c + 0) * HS + r0);
    float4 a1 = *(const float4*)(As + (c + 1) * HS + r0);
    float4 a2 = *(const float4*)(As + (c + 2) * HS + r0);
    float4 a3 = *(const float4*)(As + (c + 3) * HS + r0);
#pragma unroll
    for (int j = 0; j < ROWS; ++j) {
      int k = g + 32 * j;
      if (k < FIN) {
        float4 h4 = *(const float4*)(H + k * HS + c);
        acc[j][0] = fmaf(h4.x, a0.x, acc[j][0]); acc[j][1] = fmaf(h4.x, a0.y, acc[j][1]);
        acc[j][2] = fmaf(h4.x, a0.z, acc[j][2]); acc[j][3] = fmaf(h4.x, a0.w, acc[j][3]);
        acc[j][0] = fmaf(h4.y, a1.x, acc[j][0]); acc[j][1] = fmaf(h4.y, a1.y, acc[j][1]);
        acc[j][2] = fmaf(h4.y, a1.z, acc[j][2]); acc[j][3] = fmaf(h4.y, a1.w, acc[j][3]);
        acc[j][0] = fmaf(h4.z, a2.x, acc[j][0]); acc[j][1] = fmaf(h4.z, a2.y, acc[j][1]);
        acc[j][2] = fmaf(h4.z, a2.z, acc[j][2]); acc[j][3] = fmaf(h4.z, a2.w, acc[j][3]);
        acc[j][0] = fmaf(h4.w, a3.x, acc[j][0]); acc[j][1] = fmaf(h4.w, a3.y, acc[j][1]);
        acc[j][2] = fmaf(h4.w, a3.z, acc[j][2]); acc[j][3] = fmaf(h4.w, a3.w, acc[j][3]);
      }
    }
  }
#pragma unroll
  for (int j = 0; j < ROWS; ++j) {
    int k = g + 32 * j;
    if (k < FIN) {
#pragma unroll
      for (int i = 0; i < 4; ++i)
        Hb[(r0 + i) * HBS + k] = f2bf(acc[j][i]);
    }
  }
}

// ---------------------------------------------------------------------------
// MFMA mm: D[m][f] = sum_k Hb[m][k] * Wt[f][k] (+bias, relu / pool).
// A-frag: lane reads Hb[m=mt*16+(L&15)][ks*32 + q*8 ..+7]  (1 ds_read_b128)
// B-frag: lane reads Wt[f=nt*16+(L&15)][ks*32 + q*8 ..+7]  (1 glb b128, 64B coalesced)
// C/D:    lane holds rows mt*16+q*4..+3 at col f (verified m89 mapping).
template<int KSTEPS, int NT, int KP, int FOUT, bool POOL>
__device__ __forceinline__ void mm_mfma(const short* __restrict__ Hb,
                                        const short* __restrict__ Wt,
                                        const float* __restrict__ bias,
                                        float* __restrict__ Hout,
                                        unsigned* __restrict__ gmax, int t) {
  const int w = t >> 6;
  const int L = t & 63;
  const int q = L >> 4;
  const int mt = w & 1;                 // wave -> fixed m-tile (A-frag reuse)
  const int m = mt * 16 + (L & 15);
  short8v afrag[KSTEPS];
#pragma unroll
  for (int s = 0; s < KSTEPS; ++s)
    afrag[s] = *(const short8v*)(Hb + m * HBS + s * 32 + q * 8);
  for (int nt = (w >> 1); nt < NT; nt += 2) {
    const int f = nt * 16 + (L & 15);
    float4v acc = {0.f, 0.f, 0.f, 0.f};
#pragma unroll
    for (int s = 0; s < KSTEPS; ++s) {
      short8v bfrag = *(const short8v*)(Wt + (size_t)f * KP + s * 32 + q * 8);
      acc = __builtin_amdgcn_mfma_f32_16x16x32_bf16(afrag[s], bfrag, acc, 0, 0, 0);
    }
    if (f < FOUT) {
      float bb = bias[f];
      float o0 = fmaxf(acc[0] + bb, 0.f), o1 = fmaxf(acc[1] + bb, 0.f);
      float o2 = fmaxf(acc[2] + bb, 0.f), o3 = fmaxf(acc[3] + bb, 0.f);
      if constexpr (POOL) {
        float mx = fmaxf(fmaxf(o0, o1), fmaxf(o2, o3));
        atomicMax(&gmax[f], __float_as_uint(mx));   // relu'd >= 0 -> monotone
      } else {
        float4 o = {o0, o1, o2, o3};
        *(float4*)(Hout + f * HS + mt * 16 + q * 4) = o;
      }
    }
  }
}

// ---------------------------------------------------------------------------
// Weight pre-pack: Wt[f][k] = bf16(W[k][f]), zero-padded to Np x Kp.
__global__ __launch_bounds__(256)
void pack_wt(const float* __restrict__ src, short* __restrict__ dst,
             int FIN, int FOUT, int Kp, int Np) {
  int idx = blockIdx.x * 256 + threadIdx.x;
  if (idx >= Np * Kp) return;
  int f = idx / Kp, k = idx - f * Kp;
  float v = (f < FOUT && k < FIN) ? src[(size_t)k * FOUT + f] : 0.f;
  dst[idx] = f2bf(v);
}

// ---------------------------------------------------------------------------
// One block per graph, blockIdx.y = drug. LDS 49056 B -> 3 blocks/CU.
__global__ __launch_bounds__(256, 3)
void drug_kernel(const float* __restrict__ x1, const int* __restrict__ ei1,
                 const float* __restrict__ x2, const int* __restrict__ ei2,
                 const short* __restrict__ Wt1, const float* __restrict__ b1,
                 const short* __restrict__ Wt2, const float* __restrict__ b2,
                 const short* __restrict__ Wt3, const float* __restrict__ b3,
                 const float* __restrict__ Wg1, const float* __restrict__ bg1,
                 const float* __restrict__ Wg2, const float* __restrict__ bg2,
                 float* __restrict__ gout) {
  __shared__ __align__(16) float X[F2C * HS];    // 22464 B
  __shared__ __align__(16) float Y[FXD * HS];    // 11232 B
  __shared__ __align__(16) float As[NPG * HS];   //  4608 B
  __shared__ __align__(16) short Hb[NPG * HBS];  // 10752 B bf16 node-major
  // aliases into Y (lifetimes disjoint):
  float* deg = Y;
  float* gbuf = Y;
  unsigned* gbufU = (unsigned*)Y;
  float* gg = Y + 512;

  const int t = threadIdx.x;
  const int gid = blockIdx.x;
  const int drug = blockIdx.y;
  const float* __restrict__ x = drug ? x2 : x1;
  const int* __restrict__ ei = drug ? ei2 : ei1;
  const int nbase = gid * NPG;

  // ---- P0: zero deg/As/Hb, load x^T -> X
  if (t < NPG) deg[t] = 0.f;
  for (int i = t; i < NPG * HS; i += 256) As[i] = 0.f;
  for (int i = t; i < NPG * HBS / 2; i += 256) ((int*)Hb)[i] = 0;
  const float* xg = x + (size_t)gid * (NPG * FXD);
  for (int i = t; i < (NPG * FXD) / 4; i += 256) {
    float4 v = ((const float4*)xg)[i];
    const float* vp = (const float*)&v;
    int idx = i * 4;
#pragma unroll
    for (int j = 0; j < 4; ++j) {
      int id2 = idx + j;
      int n = id2 / FXD;
      int k = id2 - n * FXD;
      X[k * HS + n] = vp[j];
    }
  }
  int s = 0, d = 0;
  if (t < EPG) {
    s = ei[(size_t)gid * EPG + t] - nbase;
    d = ei[(size_t)N_EDGESC + (size_t)gid * EPG + t] - nbase;
  }
  __syncthreads();
  if (t < EPG) atomicAdd(&deg[s], 1.0f);
  __syncthreads();
  if (t < EPG) {
    float w = rsqrtf(deg[s] + 1.0f) * rsqrtf(deg[d] + 1.0f);
    atomicAdd(&As[d * HS + s], w);   // A[s][d]: msg d->s
  }
  if (t < NPG) atomicAdd(&As[t * HS + t], 1.0f / (deg[t] + 1.0f));
  __syncthreads();

  // ---- layer 1: A*x -> Hb ; MFMA (Hb @ Wt1) -> Y (78x36 fp32)
  a_mult_bf<FXD, 3>(X, As, Hb, t);          // deg dead after this barrier
  __syncthreads();
  mm_mfma<3, 5, 96, FXD, false>(Hb, Wt1, b1, Y, nullptr, t);
  __syncthreads();
  // ---- layer 2
  a_mult_bf<FXD, 3>(Y, As, Hb, t);
  __syncthreads();
  mm_mfma<3, 10, 96, F2C, false>(Hb, Wt2, b2, X, nullptr, t);
  __syncthreads();
  // ---- layer 3 + pool (Y dead: gbuf lives there)
  a_mult_bf<F2C, 5>(X, As, Hb, t);
  for (int i = t; i < F3C; i += 256) gbufU[i] = 0u;
  __syncthreads();
  mm_mfma<5, 20, 160, F3C, true>(Hb, Wt3, b3, nullptr, gbufU, t);
  __syncthreads();

  // ---- graph MLP (fp32)
  if (t < GHC) {
    float acc = 0.f;
#pragma unroll 2
    for (int k = 0; k < F3C; k += 4) {
      float4 gv = *(const float4*)(gbuf + k);
      acc = fmaf(gv.x, Wg1[(k + 0) * GHC + t], acc);
      acc = fmaf(gv.y, Wg1[(k + 1) * GHC + t], acc);
      acc = fmaf(gv.z, Wg1[(k + 2) * GHC + t], acc);
      acc = fmaf(gv.w, Wg1[(k + 3) * GHC + t], acc);
    }
    gg[t] = fmaxf(acc + bg1[t], 0.f);
  }
  __syncthreads();
  if (t < GOC) {
    float acc = 0.f;
#pragma unroll 2
    for (int k = 0; k < GHC; k += 4) {
      float4 gv = *(const float4*)(gg + k);
      acc = fmaf(gv.x, Wg2[(k + 0) * GOC + t], acc);
      acc = fmaf(gv.y, Wg2[(k + 1) * GOC + t], acc);
      acc = fmaf(gv.z, Wg2[(k + 2) * GOC + t], acc);
      acc = fmaf(gv.w, Wg2[(k + 3) * GOC + t], acc);
    }
    gout[((size_t)drug * N_GRAPHSC + gid) * GOC + t] = acc + bg2[t];
  }
}

// ---------------------------------------------------------------------------
// Cell MLP (R3-proven): 16 rows/block, 4x8 microtile.
__global__ __launch_bounds__(256, 3)
void cell_kernel(const float* __restrict__ cell,
                 const float* __restrict__ Wr1, const float* __restrict__ br1,
                 const float* __restrict__ Wr2, const float* __restrict__ br2,
                 const float* __restrict__ Wr3, const float* __restrict__ br3,
                 float* __restrict__ cout) {
  __shared__ __align__(16) float U[512 * RBK];
  __shared__ __align__(16) float h2[256 * RBK];
  const int t = threadIdx.x;
  const int R = blockIdx.x * RBK;
  const int r0 = (t & 3) * 4;
  const int f = t >> 2;

  float acc[4][8];
#pragma unroll
  for (int i = 0; i < 4; ++i)
#pragma unroll
    for (int j = 0; j < 8; ++j) acc[i][j] = 0.f;

  for (int k0 = 0; k0 < 1000; k0 += 200) {
    __syncthreads();
    for (int i = t; i < 800; i += 256) {
      int r = i / 50, k4 = i - r * 50;
      float4 v = *(const float4*)(cell + (size_t)(R + r) * 1000 + k0 + k4 * 4);
      int kk = k4 * 4;
      U[(kk + 0) * RBK + r] = v.x; U[(kk + 1) * RBK + r] = v.y;
      U[(kk + 2) * RBK + r] = v.z; U[(kk + 3) * RBK + r] = v.w;
    }
    __syncthreads();
#pragma unroll 4
    for (int k = 0; k < 200; ++k) {
      float4 h = *(const float4*)(U + k * RBK + r0);
      const float* wr = Wr1 + (size_t)(k0 + k) * 512 + f;
#pragma unroll
      for (int j = 0; j < 8; ++j) {
        float w = wr[j * 64];
        acc[0][j] = fmaf(h.x, w, acc[0][j]);
        acc[1][j] = fmaf(h.y, w, acc[1][j]);
        acc[2][j] = fmaf(h.z, w, acc[2][j]);
        acc[3][j] = fmaf(h.w, w, acc[3][j]);
      }
    }
  }
  __syncthreads();
#pragma unroll
  for (int j = 0; j < 8; ++j) {
    int ff = f + j * 64;
    float bb = br1[ff];
    float4 o;
    o.x = fmaxf(acc[0][j] + bb, 0.f); o.y = fmaxf(acc[1][j] + bb, 0.f);
    o.z = fmaxf(acc[2][j] + bb, 0.f); o.w = fmaxf(acc[3][j] + bb, 0.f);
    *(float4*)(U + ff * RBK + r0) = o;
  }
  __syncthreads();

  float a2[4][4];
#pragma unroll
  for (int i = 0; i < 4; ++i)
#pragma unroll
    for (int j = 0; j < 4; ++j) a2[i][j] = 0.f;
#pragma unroll 4
  for (int k = 0; k < 512; ++k) {
    float4 h = *(const float4*)(U + k * RBK + r0);
    const float* wr = Wr2 + (size_t)k * 256 + f;
#pragma unroll
    for (int j = 0; j < 4; ++j) {
      float w = wr[j * 64];
      a2[0][j] = fmaf(h.x, w, a2[0][j]);
      a2[1][j] = fmaf(h.y, w, a2[1][j]);
      a2[2][j] = fmaf(h.z, w, a2[2][j]);
      a2[3][j] = fmaf(h.w, w, a2[3][j]);
    }
  }
#pragma unroll
  for (int j = 0; j < 4; ++j) {
    int ff = f + j * 64;
    float bb = br2[ff];
    float4 o;
    o.x = fmaxf(a2[0][j] + bb, 0.f); o.y = fmaxf(a2[1][j] + bb, 0.f);
    o.z = fmaxf(a2[2][j] + bb, 0.f); o.w = fmaxf(a2[3][j] + bb, 0.f);
    *(float4*)(h2 + ff * RBK + r0) = o;
  }
  __syncthreads();

  float a3[4][2];
#pragma unroll
  for (int i = 0; i < 4; ++i) { a3[i][0] = 0.f; a3[i][1] = 0.f; }
#pragma unroll 4
  for (int k = 0; k < 256; ++k) {
    float4 h = *(const float4*)(h2 + k * RBK + r0);
    const float* wr = Wr3 + (size_t)k * 128 + f;
#pragma unroll
    for (int j = 0; j < 2; ++j) {
      float w = wr[j * 64];
      a3[0][j] = fmaf(h.x, w, a3[0][j]);
      a3[1][j] = fmaf(h.y, w, a3[1][j]);
      a3[2][j] = fmaf(h.z, w, a3[2][j]);
      a3[3][j] = fmaf(h.w, w, a3[3][j]);
    }
  }
#pragma unroll
  for (int j = 0; j < 2; ++j) {
    int ff = f + j * 64;
    float bb = br3[ff];
#pragma unroll
    for (int i = 0; i < 4; ++i)
      cout[(size_t)(R + r0 + i) * GOC + ff] = a3[i][j] + bb;
  }
}

// ---------------------------------------------------------------------------
// Head (R3-proven): 16 rows/block.
__global__ __launch_bounds__(256, 3)
void head_kernel(const float* __restrict__ g1, const float* __restrict__ g2,
                 const float* __restrict__ cc,
                 const float* __restrict__ Wf1, const float* __restrict__ bf1,
                 const float* __restrict__ Wf2, const float* __restrict__ bf2,
                 const float* __restrict__ Wo, const float* __restrict__ bo,
                 const float* __restrict__ pa, float* __restrict__ out) {
  __shared__ __align__(16) float U[512 * RBK];
  __shared__ __align__(16) float h2[128 * RBK];
  __shared__ float ssq[RBK];
  __shared__ float scal[RBK];
  __shared__ float red[256];

  const int t = threadIdx.x;
  const int R = blockIdx.x * RBK;
  if (t < RBK) ssq[t] = 0.f;
  __syncthreads();
  for (int i = t; i < 1536; i += 256) {
    int r = i / 96, qq = i - r * 96;
    int col = qq * 4;
    const float* src;
    int c2;
    if (col < 128)      { src = g1; c2 = col; }
    else if (col < 256) { src = g2; c2 = col - 128; }
    else                { src = cc; c2 = col - 256; }
    float4 v = *(const float4*)(src + (size_t)(R + r) * GOC + c2);
    U[(col + 0) * RBK + r] = v.x; U[(col + 1) * RBK + r] = v.y;
    U[(col + 2) * RBK + r] = v.z; U[(col + 3) * RBK + r] = v.w;
    atomicAdd(&ssq[r], v.x * v.x + v.y * v.y + v.z * v.z + v.w * v.w);
  }
  __syncthreads();
  if (t < RBK) scal[t] = 1.0f / fmaxf(sqrtf(ssq[t]), 1e-12f);
  __syncthreads();

  const float a = pa[0];
  const int r0 = (t & 3) * 4;
  const int f = t >> 2;

  float acc[4][8];
#pragma unroll
  for (int i = 0; i < 4; ++i)
#pragma unroll
    for (int j = 0; j < 8; ++j) acc[i][j] = 0.f;
#pragma unroll 4
  for (int k = 0; k < 384; ++k) {
    float4 h = *(const float4*)(U + k * RBK + r0);
    const float* wr = Wf1 + (size_t)k * 512 + f;
#pragma unroll
    for (int j = 0; j < 8; ++j) {
      float w = wr[j * 64];
      acc[0][j] = fmaf(h.x, w, acc[0][j]);
      acc[1][j] = fmaf(h.y, w, acc[1][j]);
      acc[2][j] = fmaf(h.z, w, acc[2][j]);
      acc[3][j] = fmaf(h.w, w, acc[3][j]);
    }
  }
  __syncthreads();
#pragma unroll
  for (int j = 0; j < 8; ++j) {
    int ff = f + j * 64;
    float bb = bf1[ff];
    float4 o;
    float v0 = acc[0][j] * scal[r0 + 0] + bb; o.x = v0 >= 0.f ? v0 : a * v0;
    float v1 = acc[1][j] * scal[r0 + 1] + bb; o.y = v1 >= 0.f ? v1 : a * v1;
    float v2 = acc[2][j] * scal[r0 + 2] + bb; o.z = v2 >= 0.f ? v2 : a * v2;
    float v3 = acc[3][j] * scal[r0 + 3] + bb; o.w = v3 >= 0.f ? v3 : a * v3;
    *(float4*)(U + ff * RBK + r0) = o;
  }
  __syncthreads();

  float a2[4][2];
#pragma unroll
  for (int i = 0; i < 4; ++i) { a2[i][0] = 0.f; a2[i][1] = 0.f; }
#pragma unroll 4
  for (int k = 0; k < 512; ++k) {
    float4 h = *(const float4*)(U + k * RBK + r0);
    const float* wr = Wf2 + (size_t)k * 128 + f;
#pragma unroll
    for (int j = 0; j < 2; ++j) {
      float w = wr[j * 64];
      a2[0][j] = fmaf(h.x, w, a2[0][j]);
      a2[1][j] = fmaf(h.y, w, a2[1][j]);
      a2[2][j] = fmaf(h.z, w, a2[2][j]);
      a2[3][j] = fmaf(h.w, w, a2[3][j]);
    }
  }
  {
#pragma unroll
    for (int j = 0; j < 2; ++j) {
      int ff = f + j * 64;
      float bb = bf2[ff];
#pragma unroll
      for (int i = 0; i < 4; ++i) {
        float v = a2[i][j] + bb;
        v = v >= 0.f ? v : a * v;
        h2[ff * RBK + (r0 + i)] = v;
      }
    }
  }
  __syncthreads();

  {
    int rr = t >> 4, kp = t & 15;
    float p = 0.f;
#pragma unroll
    for (int jj = 0; jj < 8; ++jj) {
      int k = kp + 16 * jj;
      p = fmaf(h2[k * RBK + rr], Wo[k], p);
    }
    red[t] = p;
  }
  __syncthreads();
  if (t < RBK) {
    float ssum = bo[0];
#pragma unroll
    for (int i = 0; i < 16; ++i) ssum += red[t * 16 + i];
    out[R + t] = 1.0f / (1.0f + expf(-ssum));
  }
}

// ---------------------------------------------------------------------------
extern "C" void kernel_launch(void* const* d_in, const int* in_sizes, int n_in,
                              void* d_out, int out_size, void* d_ws, size_t ws_size,
                              hipStream_t stream) {
  const float* x1  = (const float*)d_in[0];
  const int*   ei1 = (const int*)d_in[1];
  const float* x2  = (const float*)d_in[2];
  const int*   ei2 = (const int*)d_in[3];
  const float* cel = (const float*)d_in[4];
  const float* W1  = (const float*)d_in[7];
  const float* b1  = (const float*)d_in[8];
  const float* W2  = (const float*)d_in[9];
  const float* b2  = (const float*)d_in[10];
  const float* W3  = (const float*)d_in[11];
  const float* b3  = (const float*)d_in[12];
  const float* Wg1 = (const float*)d_in[13];
  const float* bg1 = (const float*)d_in[14];
  const float* Wg2 = (const float*)d_in[15];
  const float* bg2 = (const float*)d_in[16];
  const float* Wr1 = (const float*)d_in[17];
  const float* br1 = (const float*)d_in[18];
  const float* Wr2 = (const float*)d_in[19];
  const float* br2 = (const float*)d_in[20];
  const float* Wr3 = (const float*)d_in[21];
  const float* br3 = (const float*)d_in[22];
  const float* Wf1 = (const float*)d_in[23];
  const float* bf1 = (const float*)d_in[24];
  const float* Wf2 = (const float*)d_in[25];
  const float* bf2 = (const float*)d_in[26];
  const float* Wo  = (const float*)d_in[27];
  const float* bo  = (const float*)d_in[28];
  const float* pa  = (const float*)d_in[29];

  float* ws    = (float*)d_ws;
  float* g1buf = ws;
  float* g2buf = ws + (size_t)N_GRAPHSC * GOC;
  float* cbuf  = ws + (size_t)2 * N_GRAPHSC * GOC;
  short* wt1   = (short*)(ws + (size_t)3 * N_GRAPHSC * GOC);  // 80x96
  short* wt2   = wt1 + 80 * 96;                               // 160x96
  short* wt3   = wt2 + 160 * 96;                              // 320x160
  float* outp  = (float*)d_out;

  pack_wt<<<dim3((80 * 96 + 255) / 256), dim3(256), 0, stream>>>(W1, wt1, FXD, FXD, 96, 80);
  pack_wt<<<dim3((160 * 96 + 255) / 256), dim3(256), 0, stream>>>(W2, wt2, FXD, F2C, 96, 160);
  pack_wt<<<dim3((320 * 160 + 255) / 256), dim3(256), 0, stream>>>(W3, wt3, F2C, F3C, 160, 320);

  dim3 dgrid(N_GRAPHSC, 2);
  drug_kernel<<<dgrid, dim3(256), 0, stream>>>(
      x1, ei1, x2, ei2, wt1, b1, wt2, b2, wt3, b3, Wg1, bg1, Wg2, bg2, g1buf);
  cell_kernel<<<dim3(N_GRAPHSC / RBK), dim3(256), 0, stream>>>(
      cel, Wr1, br1, Wr2, br2, Wr3, br3, cbuf);
  head_kernel<<<dim3(N_GRAPHSC / RBK), dim3(256), 0, stream>>>(
      g1buf, g2buf, cbuf, Wf1, bf1, Wf2, bf2, Wo, bo, pa, outp);
}